// Round 10
// baseline (85.692 us; speedup 1.0000x reference)
//
#include <hip/hip_runtime.h>
#include <hip/hip_bf16.h>
#include <math.h>

// DistWeightLoss on MI355X — round 10: barrier-free streaming.
// Xbf is 2 MB => L2-resident. Drop LDS staging entirely; each wave holds its
// 32 A-rows in registers and streams B fragments straight from L2 to regs.
// No __syncthreads / vmcnt drains in the hot loop (r3-r9 plateau was the
// 2-phase stage->drain->barrier critical path, not any pipe). Per-thread
// VGPR demand ~100 (r5/r8/r9 spill rule: keep <=110).
//
// ws layout: [0:N) pos_min f32 | [N:2N) row_sum f32 | [2N:3N) row_cnt f32
//            | [3N:) Xbf bf16 [N][D]
//   A) pos_kernel: per-class 8x8 Gram (fp32, exact) + fused fp32->bf16 cvt
//      + zero-init of row_sum/row_cnt. Exact JAX Threefry gumbel -> pos_min.
//   B) neg_stream_kernel: grid 64x16 = 1024 blocks (4/CU), 256 thr = 4 waves.
//      Wave = 32 rows (areg[2][4] in VGPRs) x 32-col steps over a 512-col
//      j-chunk (16 steps). B frags via global_load_dwordx4 (L2-hit; 4 waves
//      of a block share lines via L1). Register mask-accum; 16-lane shfl
//      reduce + 2 atomics per row per block.
//   C) finalize_kernel: loss = sum(valid? s/c - pos + m : 0)/N.

#define NN 8192
#define DD 128
#define KK 8
#define MARGIN 0.01f

#define ROWB 128       // rows per block (4 waves x 32)
#define WROW 32        // rows per wave
#define JCW 512        // j-chunk per block
#define JSTEP 32       // cols per step
#define JT (JCW / JSTEP)  // 16 steps

typedef __attribute__((ext_vector_type(8))) short short8;
typedef __attribute__((ext_vector_type(4))) float f32x4;

// ---------------- Threefry2x32 / JAX gumbel (bit-exact, validated) ----------------
__device__ __forceinline__ unsigned rotl32(unsigned x, unsigned r) {
    return (x << r) | (x >> (32u - r));
}

__device__ float gumbel_at(unsigned m) {
    const unsigned HALF = (NN * (KK - 1)) / 2;  // 28672
    unsigned c   = (m < HALF) ? m : (m - HALF);
    bool     hi  = (m >= HALF);
    const unsigned ks0 = 0u, ks1 = 42u;
    const unsigned ks2 = 0x1BD11BDAu ^ ks0 ^ ks1;
    unsigned x0 = c + ks0;
    unsigned x1 = (c + HALF) + ks1;
#define TF_ROUND(r) { x0 += x1; x1 = rotl32(x1, (r)); x1 ^= x0; }
    TF_ROUND(13) TF_ROUND(15) TF_ROUND(26) TF_ROUND(6)
    x0 += ks1; x1 += ks2 + 1u;
    TF_ROUND(17) TF_ROUND(29) TF_ROUND(16) TF_ROUND(24)
    x0 += ks2; x1 += ks0 + 2u;
    TF_ROUND(13) TF_ROUND(15) TF_ROUND(26) TF_ROUND(6)
    x0 += ks0; x1 += ks1 + 3u;
    TF_ROUND(17) TF_ROUND(29) TF_ROUND(16) TF_ROUND(24)
    x0 += ks1; x1 += ks2 + 4u;
    TF_ROUND(13) TF_ROUND(15) TF_ROUND(26) TF_ROUND(6)
    x0 += ks2; x1 += ks0 + 5u;
#undef TF_ROUND
    unsigned bits = hi ? x1 : x0;
    float f = __uint_as_float((bits >> 9) | 0x3f800000u) - 1.0f;
    float u = fmaxf(f, 1.17549435e-38f);
    return -logf(-logf(u));
}

// ---------------- fp32 -> bf16 (RNE) ----------------
__device__ __forceinline__ unsigned short bf16r(float f) {
    unsigned u = __float_as_uint(f);
    unsigned r = (u + 0x7FFFu + ((u >> 16) & 1u)) >> 16;
    return (unsigned short)r;
}

// ---------------- Kernel A: pos_min + cvt + zero-init ----------------
__global__ __launch_bounds__(64) void pos_kernel(const float* __restrict__ X,
                                                 float* __restrict__ pos_min,
                                                 float* __restrict__ row_sum,
                                                 float* __restrict__ row_cnt,
                                                 unsigned short* __restrict__ Xbf) {
    __shared__ float Xc[KK * DD];
    __shared__ float gram[KK * KK];
    const int c   = blockIdx.x;
    const int tid = threadIdx.x;

    if (tid < KK) {
        row_sum[c * KK + tid] = 0.f;
        row_cnt[c * KK + tid] = 0.f;
    }

    const float4* src = (const float4*)(X + (size_t)c * KK * DD);
    float4*       dst = (float4*)Xc;
#pragma unroll
    for (int it = 0; it < (KK * DD / 4) / 64; ++it)
        dst[tid + it * 64] = src[tid + it * 64];
    __syncthreads();

    ushort4* obf = (ushort4*)(Xbf + (size_t)c * KK * DD);
#pragma unroll
    for (int it = 0; it < 4; ++it) {
        int idx = tid + it * 64;
        float4 v = ((const float4*)Xc)[idx];
        ushort4 o;
        o.x = bf16r(v.x); o.y = bf16r(v.y); o.z = bf16r(v.z); o.w = bf16r(v.w);
        obf[idx] = o;
    }

    const int a = tid >> 3, b = tid & 7;
    float s = 0.f;
#pragma unroll
    for (int k = 0; k < DD; k += 4) {
        float4 va = *(const float4*)&Xc[a * DD + k];
        float4 vb = *(const float4*)&Xc[b * DD + k];
        s += va.x * vb.x + va.y * vb.y + va.z * vb.z + va.w * vb.w;
    }
    gram[a * KK + b] = s;
    __syncthreads();

    if (tid < KK) {
        const int r = tid;
        const int i = c * KK + r;
        float ps[KK - 1];
#pragma unroll
        for (int jj = 0; jj < KK - 1; ++jj)
            ps[jj] = gram[r * KK + ((r + 1 + jj) & (KK - 1))];
#pragma unroll
        for (int p = 0; p < KK - 2; ++p)
#pragma unroll
            for (int q = 0; q < KK - 2 - p; ++q) {
                float lo = fminf(ps[q], ps[q + 1]);
                float hi = fmaxf(ps[q], ps[q + 1]);
                ps[q] = lo; ps[q + 1] = hi;
            }
        float best = -1e30f;
        float pmin = ps[0];
#pragma unroll
        for (int jj = 0; jj < KK - 1; ++jj) {
            float g  = gumbel_at((unsigned)(i * (KK - 1) + jj));
            float sc = 5.0f * ps[jj] + g;
            if (sc > best) { best = sc; pmin = ps[jj]; }
        }
        pos_min[i] = pmin;
    }
}

// ---------------- Kernel B: barrier-free L2->reg streaming MFMA ----------------
__global__ __launch_bounds__(256) void neg_stream_kernel(const unsigned short* __restrict__ Xbf,
                                                         const float* __restrict__ pos_min,
                                                         float* __restrict__ row_sum,
                                                         float* __restrict__ row_cnt) {
    const int tid  = threadIdx.x;
    const int lane = tid & 63;
    const int w    = tid >> 6;      // 0..3 : which 32-row band of the block
    const int l15  = lane & 15, l4 = lane >> 4;
    const int iw   = blockIdx.x * ROWB + w * WROW;  // this wave's first row
    const int j0   = blockIdx.y * JCW;

    // ---- A fragments -> registers (held for the whole j-stream)
    short8 areg[2][4];
#pragma unroll
    for (int m = 0; m < 2; ++m) {
        const int row = iw + m * 16 + l15;
#pragma unroll
        for (int kk = 0; kk < 4; ++kk)
            areg[m][kk] = *(const short8*)(Xbf + (((size_t)row) << 7) + kk * 32 + l4 * 8);
    }

    // per-lane thresholds / class ids for the 8 rows this lane reduces
    float thr[2][4];
    int   i3[2];
#pragma unroll
    for (int m = 0; m < 2; ++m) {
        const int ib = iw + m * 16 + l4 * 4;
        i3[m] = ib >> 3;  // rows ib..ib+3 share one class (4-aligned quad in 8-block)
#pragma unroll
        for (int r = 0; r < 4; ++r) thr[m][r] = pos_min[ib + r] - MARGIN;
    }
    float s[2][4] = {{0.f}}, c[2][4] = {{0.f}};

    for (int t = 0; t < JT; ++t) {
        const int jt0 = j0 + t * JSTEP;

        f32x4 acc[2][2] = {};
#pragma unroll
        for (int kk = 0; kk < 4; ++kk) {
            short8 b[2];
#pragma unroll
            for (int n = 0; n < 2; ++n) {
                const int rb = jt0 + n * 16 + l15;
                b[n] = *(const short8*)(Xbf + (((size_t)rb) << 7) + kk * 32 + l4 * 8);
            }
#pragma unroll
            for (int m = 0; m < 2; ++m)
#pragma unroll
                for (int n = 0; n < 2; ++n)
                    acc[m][n] = __builtin_amdgcn_mfma_f32_16x16x32_bf16(areg[m][kk], b[n], acc[m][n], 0, 0, 0);
        }

        // mask-accumulate (C/D layout: col=lane&15, row=(lane>>4)*4+reg)
        const bool sdiag = (jt0 < iw + WROW) && (iw < jt0 + JSTEP);
        if (sdiag) {
#pragma unroll
            for (int n = 0; n < 2; ++n) {
                const int j3 = (jt0 + n * 16 + l15) >> 3;
#pragma unroll
                for (int m = 0; m < 2; ++m)
#pragma unroll
                    for (int r = 0; r < 4; ++r) {
                        float v = acc[m][n][r];
                        bool k = (v > thr[m][r]) && (i3[m] != j3);
                        s[m][r] += k ? v : 0.f;
                        c[m][r] += k ? 1.f : 0.f;
                    }
            }
        } else {
#pragma unroll
            for (int n = 0; n < 2; ++n)
#pragma unroll
                for (int m = 0; m < 2; ++m)
#pragma unroll
                    for (int r = 0; r < 4; ++r) {
                        float v = acc[m][n][r];
                        bool k = (v > thr[m][r]);
                        s[m][r] += k ? v : 0.f;
                        c[m][r] += k ? 1.f : 0.f;
                    }
        }
    }

    // ---- per-wave: reduce across the 16 col-lanes, then atomics
#pragma unroll
    for (int m = 0; m < 2; ++m)
#pragma unroll
        for (int r = 0; r < 4; ++r) {
            float sv = s[m][r], cv = c[m][r];
#pragma unroll
            for (int off = 1; off < 16; off <<= 1) {
                sv += __shfl_xor(sv, off);
                cv += __shfl_xor(cv, off);
            }
            if (l15 == 0) {
                int i = iw + m * 16 + l4 * 4 + r;
                atomicAdd(&row_sum[i], sv);
                atomicAdd(&row_cnt[i], cv);
            }
        }
}

// ---------------- Kernel C: finalize ----------------
__global__ __launch_bounds__(1024) void finalize_kernel(const float* __restrict__ row_sum,
                                                        const float* __restrict__ row_cnt,
                                                        const float* __restrict__ pos_min,
                                                        float* __restrict__ out) {
    __shared__ float red[1024];
    const int tid = threadIdx.x;
    float local = 0.f;
#pragma unroll
    for (int it = 0; it < NN / 1024; ++it) {
        int i = tid + it * 1024;
        float cnt = row_cnt[i];
        if (cnt > 0.f) {
            float nm = row_sum[i] / fmaxf(cnt, 1.0f);
            local += nm - pos_min[i] + MARGIN;
        }
    }
    red[tid] = local;
    __syncthreads();
    for (int st = 512; st > 0; st >>= 1) {
        if (tid < st) red[tid] += red[tid + st];
        __syncthreads();
    }
    if (tid == 0) out[0] = red[0] / (float)NN;
}

extern "C" void kernel_launch(void* const* d_in, const int* in_sizes, int n_in,
                              void* d_out, int out_size, void* d_ws, size_t ws_size,
                              hipStream_t stream) {
    const float* X = (const float*)d_in[0];
    float* pos_min = (float*)d_ws;
    float* row_sum = pos_min + NN;
    float* row_cnt = row_sum + NN;
    unsigned short* Xbf = (unsigned short*)((char*)d_ws + (size_t)3 * NN * 4);

    pos_kernel<<<NN / KK, 64, 0, stream>>>(X, pos_min, row_sum, row_cnt, Xbf);
    dim3 grid(NN / ROWB, NN / JCW);
    neg_stream_kernel<<<grid, 256, 0, stream>>>(Xbf, pos_min, row_sum, row_cnt);
    finalize_kernel<<<1, 1024, 0, stream>>>(row_sum, row_cnt, pos_min, (float*)d_out);
}